// Round 17
// baseline (289.407 us; speedup 1.0000x reference)
//
#include <hip/hip_runtime.h>

#define NUM_USERS 50000
#define NUM_ITEMS 50000
#define N_NODES   100000
#define NNZ       3200000
#define EMB_DIM   64
#define N_LAYERS  3
#define BATCH     16384

#define NBUCK 512
#define ABITS 8                  // bucket = dst >> 8 (256 nodes/bucket, 391 used)
#define NODES_PER_BUCK 256
#define TILE_EDGES 8192
#define NBUCK_USED ((N_NODES + NODES_PER_BUCK - 1) / NODES_PER_BUCK)   // 391
#define CAP 9216                 // padded bucket capacity (mean 8192, +11 sigma)
#define NWAVE 16                 // waves per 1024-thread block

typedef unsigned long long ull;

// ---- bf16 helpers (RNE) ----
__device__ inline unsigned bf16pair(float a, float b) {
    unsigned ua = __float_as_uint(a), ub = __float_as_uint(b);
    unsigned r0 = (ua + 0x7fffu + ((ua >> 16) & 1u)) >> 16;
    unsigned r1 = (ub + 0x7fffu + ((ub >> 16) & 1u)) >> 16;
    return r0 | (r1 << 16);
}
__device__ inline float blo(unsigned u) { return __uint_as_float(u << 16); }
__device__ inline float bhi(unsigned u) { return __uint_as_float(u & 0xffff0000u); }

// accumulate 8 bf16 dims (one uint4) * w into s[0..7]
__device__ inline void acc8(float* s, uint4 g, float w) {
    s[0] = fmaf(w, blo(g.x), s[0]); s[1] = fmaf(w, bhi(g.x), s[1]);
    s[2] = fmaf(w, blo(g.y), s[2]); s[3] = fmaf(w, bhi(g.y), s[3]);
    s[4] = fmaf(w, blo(g.z), s[4]); s[5] = fmaf(w, bhi(g.z), s[5]);
    s[6] = fmaf(w, blo(g.w), s[6]); s[7] = fmaf(w, bhi(g.w), s[7]);
}

// init: E0(bf16) = concat(ue, ie). Block 0 inits bucket cursors.
// Fused flag pass: flags[n]=1 for batch nodes (no zeroing: poison 0xAA != 1;
// spurious stale 1 only costs harmless extra compute in the gated pull).
__global__ void init_emb_kernel(const float* __restrict__ ue,
                                const float* __restrict__ ie,
                                unsigned* __restrict__ E0,
                                int* __restrict__ bucketCursor,
                                unsigned char* __restrict__ flags,
                                const int* __restrict__ users,
                                const int* __restrict__ items) {
    int idx = blockIdx.x * blockDim.x + threadIdx.x;   // per float4 (4 dims)
    if (blockIdx.x == 0 && threadIdx.x < 256) {
        bucketCursor[threadIdx.x]       = threadIdx.x * CAP;
        bucketCursor[threadIdx.x + 256] = (threadIdx.x + 256) * CAP;
    }
    if (idx < BATCH) {
        flags[users[idx]] = 1;
    } else if (idx < 2 * BATCH) {
        flags[NUM_USERS + items[idx - BATCH]] = 1;
    }
    const int total = N_NODES * (EMB_DIM / 4);
    if (idx >= total) return;
    const int uoff = NUM_USERS * (EMB_DIM / 4);
    float4 v;
    if (idx < uoff) v = ((const float4*)ue)[idx];
    else            v = ((const float4*)ie)[idx - uoff];
    uint2 h;
    h.x = bf16pair(v.x, v.y);
    h.y = bf16pair(v.z, v.w);
    ((uint2*)E0)[idx] = h;
}

// partA: partition edges into padded dst-bucket regions. 1024 threads, 8 edges/thread.
// PER-WAVE private histograms + cursors: each wave atomics only its own 512-slice
// (kills cross-wave LDS same-address serialization in both hist & scatter phases).
// rec: src(17) | dstLocal(8)<<17 | fix15(val)<<25
__global__ void partA_kernel(const float* __restrict__ ev,
                             const int*  __restrict__ es,
                             const int*  __restrict__ ed,
                             int* __restrict__ bucketCursor,
                             ull* __restrict__ tmp) {
    __shared__ int hist[NWAVE * NBUCK];   // 32 KB; becomes per-wave cursors after merge
    int tid = threadIdx.x;            // 1024
    int wv  = tid >> 6;               // wave 0..15
    int e0 = blockIdx.x * TILE_EDGES;

    int      mySrc[8], myDst[8];
    unsigned myQ[8];

    for (int i = tid; i < NWAVE * NBUCK; i += 1024) hist[i] = 0;
    __syncthreads();

    int* hw = hist + wv * NBUCK;
    #pragma unroll
    for (int k = 0; k < 8; ++k) {
        int e = e0 + k * 1024 + tid;
        if (e < NNZ) {
            mySrc[k] = es[e];
            myDst[k] = ed[e];
            myQ[k]   = (unsigned)fminf(ev[e] * 32768.f + 0.5f, 32767.f);
            atomicAdd(&hw[((unsigned)myDst[k]) >> ABITS], 1);
        } else {
            myDst[k] = -1;
        }
    }
    __syncthreads();

    // merge: thread t (<512) owns bucket t — sum wave counts, reserve global range,
    // write back per-wave cursor starts in place.
    if (tid < NBUCK) {
        int c[NWAVE];
        int tot = 0;
        #pragma unroll
        for (int w = 0; w < NWAVE; ++w) { c[w] = hist[w * NBUCK + tid]; tot += c[w]; }
        int run = tot ? atomicAdd(&bucketCursor[tid], tot) : 0;
        #pragma unroll
        for (int w = 0; w < NWAVE; ++w) { hist[w * NBUCK + tid] = run; run += c[w]; }
    }
    __syncthreads();

    #pragma unroll
    for (int k = 0; k < 8; ++k) {
        int dst = myDst[k];
        if (dst < 0) continue;
        int b = ((unsigned)dst) >> ABITS;
        int pos = atomicAdd(&hw[b], 1);   // wave-private cursor
        if (pos < (b + 1) * CAP) {        // statistically unreachable overflow guard
            ull rec = (ull)(unsigned)(mySrc[k] | ((dst & (NODES_PER_BUCK - 1)) << 17))
                    | ((ull)myQ[k] << 25);
            tmp[pos] = rec;
        }
    }
}

// partB: per bucket — single-pass: register-cache records (<=9/thread), node degrees
// + rowStart via LDS scan, scatter from registers to padded-CSR positions.
// sorted rec (u32): src(17) | fix15(val)<<17
__global__ void partB_kernel(const ull* __restrict__ tmp,
                             const int* __restrict__ bucketCursor,
                             int* __restrict__ rowStart,
                             int* __restrict__ deg,
                             unsigned* __restrict__ sorted) {
    __shared__ int cnt[NODES_PER_BUCK];
    __shared__ int sc[NODES_PER_BUCK];
    __shared__ int cur[NODES_PER_BUCK];
    int b = blockIdx.x;
    int tid = threadIdx.x;           // 1024
    int nodeLo = b << ABITS;
    int startE = b * CAP;
    int endE   = bucketCursor[b];    // base + edges in bucket

    if (tid < NODES_PER_BUCK) cnt[tid] = 0;
    __syncthreads();

    ull myRec[9];
    int nRec = 0;
    #pragma unroll
    for (int k = 0; k < 9; ++k) {
        int i = startE + k * 1024 + tid;
        if (i < endE) {
            myRec[k] = tmp[i];
            nRec = k + 1;
            atomicAdd(&cnt[(int)((myRec[k] >> 17) & (NODES_PER_BUCK - 1))], 1);
        }
    }
    __syncthreads();

    if (tid < NODES_PER_BUCK) sc[tid] = cnt[tid];
    __syncthreads();
    for (int o = 1; o < NODES_PER_BUCK; o <<= 1) {
        int add = 0;
        if (tid < NODES_PER_BUCK && tid >= o) add = sc[tid - o];
        __syncthreads();
        if (tid < NODES_PER_BUCK) sc[tid] += add;
        __syncthreads();
    }
    if (tid < NODES_PER_BUCK) {
        int node = nodeLo + tid;
        int rs = startE + sc[tid] - cnt[tid];
        cur[tid] = rs;
        if (node < N_NODES) {
            rowStart[node] = rs;          // index into padded sorted array
            deg[node] = cnt[tid];
        }
    }
    __syncthreads();

    for (int k = 0; k < nRec; ++k) {
        ull rec = myRec[k];
        int dl = (int)((rec >> 17) & (NODES_PER_BUCK - 1));
        unsigned o = (unsigned)(rec & 0x1FFFFULL) | ((unsigned)((rec >> 25) & 0x7FFF) << 17);
        int pos = atomicAdd(&cur[dl], 1);
        sorted[pos] = o;
    }
}

// ---- pull: one wave per dst node; lane = (eg=lane>>3, d8=lane&7).
// u32 edge records; uint4 bf16 gathers; 32 edges in flight. Byte-flag gate on last layer.
__global__ void pull_kernel(const uint4* __restrict__ A16,
                            uint4* __restrict__ B16,
                            const unsigned* __restrict__ sorted,
                            const int* __restrict__ rowStart,
                            const int* __restrict__ deg,
                            const unsigned char* __restrict__ flags,
                            int gate) {
    int t = blockIdx.x * blockDim.x + threadIdx.x;
    int node = t >> 6;
    if (node >= N_NODES) return;
    if (gate && flags[node] != 1) return;   // wave-uniform
    int lane = t & 63;
    int eg = lane >> 3;      // 0..7
    int d8 = lane & 7;       // dim octet (16 B)
    int start = rowStart[node];
    int cnt   = deg[node];   // wave-uniform
    const unsigned* ep = sorted + start;
    const float k15 = 1.f / 32768.f;

    float s[8] = {0.f,0.f,0.f,0.f,0.f,0.f,0.f,0.f};
    int j = 0;
    while (j + 32 <= cnt) {
        unsigned r0 = ep[j + eg], r1 = ep[j + 8 + eg];
        unsigned r2 = ep[j + 16 + eg], r3 = ep[j + 24 + eg];
        uint4 g0 = A16[(((long long)(r0 & 0x1FFFFu)) << 3) + d8];
        uint4 g1 = A16[(((long long)(r1 & 0x1FFFFu)) << 3) + d8];
        uint4 g2 = A16[(((long long)(r2 & 0x1FFFFu)) << 3) + d8];
        uint4 g3 = A16[(((long long)(r3 & 0x1FFFFu)) << 3) + d8];
        acc8(s, g0, (float)(r0 >> 17) * k15);
        acc8(s, g1, (float)(r1 >> 17) * k15);
        acc8(s, g2, (float)(r2 >> 17) * k15);
        acc8(s, g3, (float)(r3 >> 17) * k15);
        j += 32;
    }
    while (j + 16 <= cnt) {
        unsigned r0 = ep[j + eg], r1 = ep[j + 8 + eg];
        uint4 g0 = A16[(((long long)(r0 & 0x1FFFFu)) << 3) + d8];
        uint4 g1 = A16[(((long long)(r1 & 0x1FFFFu)) << 3) + d8];
        acc8(s, g0, (float)(r0 >> 17) * k15);
        acc8(s, g1, (float)(r1 >> 17) * k15);
        j += 16;
    }
    for (; j < cnt; j += 8) {
        int idx = j + eg;
        unsigned r = (idx < cnt) ? ep[idx] : 0u;   // r=0 -> w=0
        uint4 g = A16[(((long long)(r & 0x1FFFFu)) << 3) + d8];
        acc8(s, g, (float)(r >> 17) * k15);
    }
    #pragma unroll
    for (int k = 0; k < 8; ++k) {
        s[k] += __shfl_xor(s[k], 8, 64);
        s[k] += __shfl_xor(s[k], 16, 64);
        s[k] += __shfl_xor(s[k], 32, 64);
    }
    if (eg == 0) {
        uint4 h;
        h.x = bf16pair(s[0], s[1]);
        h.y = bf16pair(s[2], s[3]);
        h.z = bf16pair(s[4], s[5]);
        h.w = bf16pair(s[6], s[7]);
        B16[(((long long)node) << 3) + d8] = h;
    }
}

// dot: half-wave (32 lanes) per batch element; lane covers 2 dims (one uint).
// gamma = dot( sum_l U_l , sum_l I_l ) / 16, layers read from E0,B1,B2,B3.
__global__ void dot_kernel(const unsigned* __restrict__ E0,
                           const unsigned* __restrict__ B1,
                           const unsigned* __restrict__ B2,
                           const unsigned* __restrict__ B3,
                           const int* __restrict__ users,
                           const int* __restrict__ items,
                           float* __restrict__ out) {
    int t = blockIdx.x * blockDim.x + threadIdx.x;
    int b = t >> 5;
    int lane = t & 31;
    if (b >= BATCH) return;
    long long uo = ((long long)users[b] << 5) + lane;
    long long io = ((long long)(items[b] + NUM_USERS) << 5) + lane;
    unsigned a0 = E0[uo], a1 = B1[uo], a2 = B2[uo], a3 = B3[uo];
    unsigned c0 = E0[io], c1 = B1[io], c2 = B2[io], c3 = B3[io];
    float ux = (blo(a0) + blo(a1)) + (blo(a2) + blo(a3));
    float uy = (bhi(a0) + bhi(a1)) + (bhi(a2) + bhi(a3));
    float ix = (blo(c0) + blo(c1)) + (blo(c2) + blo(c3));
    float iy = (bhi(c0) + bhi(c1)) + (bhi(c2) + bhi(c3));
    float p = ux * ix + uy * iy;
    #pragma unroll
    for (int off = 16; off >= 1; off >>= 1)
        p += __shfl_xor(p, off, 64);   // stays within the aligned 32-group
    if (lane == 0) out[b] = p * 0.0625f;
}

extern "C" void kernel_launch(void* const* d_in, const int* in_sizes, int n_in,
                              void* d_out, int out_size, void* d_ws, size_t ws_size,
                              hipStream_t stream) {
    const float* user_emb = (const float*)d_in[0];
    const float* item_emb = (const float*)d_in[1];
    const float* edge_val = (const float*)d_in[2];
    const int*   edge_src = (const int*)d_in[3];
    const int*   edge_dst = (const int*)d_in[4];
    const int*   users    = (const int*)d_in[5];
    const int*   items    = (const int*)d_in[6];
    float* out = (float*)d_out;

    const size_t emb16Bytes = (size_t)N_NODES * EMB_DIM * 2;               // 12.8 MB
    const size_t sortBytes  = (size_t)NBUCK_USED * CAP * sizeof(unsigned); // 14.4 MB
    const size_t tmpBytes   = (size_t)NBUCK_USED * CAP * sizeof(ull);      // 28.8 MB
    const size_t nodeBytes  = (size_t)N_NODES * sizeof(int);               // 400 KB

    char* w = (char*)d_ws;
    unsigned* E0           = (unsigned*)(w); w += emb16Bytes;
    unsigned* B1           = (unsigned*)(w); w += emb16Bytes;
    unsigned* B2           = (unsigned*)(w); w += emb16Bytes;
    unsigned* B3           = (unsigned*)(w); w += emb16Bytes;
    unsigned* sorted       = (unsigned*)(w); w += sortBytes;
    ull*      tmp          = (ull*)(w);      w += tmpBytes;
    int*      deg          = (int*)(w);      w += nodeBytes;
    int*      rowStart     = (int*)(w);      w += nodeBytes;
    int*      bucketCursor = (int*)(w);      w += NBUCK * sizeof(int);
    unsigned char* flags   = (unsigned char*)(w); w += N_NODES;

    const int vecTotal   = N_NODES * (EMB_DIM / 4);
    const int initBlocks = (vecTotal + 255) / 256;
    const int tileBlocks = (NNZ + TILE_EDGES - 1) / TILE_EDGES;   // 391

    init_emb_kernel<<<initBlocks, 256, 0, stream>>>(user_emb, item_emb, E0,
                                                    bucketCursor, flags, users, items);

    partA_kernel<<<tileBlocks, 1024, 0, stream>>>(edge_val, edge_src, edge_dst,
                                                  bucketCursor, tmp);
    partB_kernel<<<NBUCK_USED, 1024, 0, stream>>>(tmp, bucketCursor,
                                                  rowStart, deg, sorted);

    const int pullBlocks = (N_NODES * 64 + 255) / 256;
    pull_kernel<<<pullBlocks, 256, 0, stream>>>((const uint4*)E0, (uint4*)B1,
                                                sorted, rowStart, deg, flags, 0);
    pull_kernel<<<pullBlocks, 256, 0, stream>>>((const uint4*)B1, (uint4*)B2,
                                                sorted, rowStart, deg, flags, 0);
    pull_kernel<<<pullBlocks, 256, 0, stream>>>((const uint4*)B2, (uint4*)B3,
                                                sorted, rowStart, deg, flags, 1);

    const int dotBlocks = (BATCH * 32 + 255) / 256;
    dot_kernel<<<dotBlocks, 256, 0, stream>>>(E0, B1, B2, B3, users, items, out);
}

// Round 18
// 281.712 us; speedup vs baseline: 1.0273x; 1.0273x over previous
//
#include <hip/hip_runtime.h>

#define NUM_USERS 50000
#define NUM_ITEMS 50000
#define N_NODES   100000
#define NNZ       3200000
#define EMB_DIM   64
#define N_LAYERS  3
#define BATCH     16384

#define NBUCK 512
#define ABITS 8                  // bucket = dst >> 8 (256 nodes/bucket, 391 used)
#define NODES_PER_BUCK 256
#define TILE_EDGES 8192
#define NBUCK_USED ((N_NODES + NODES_PER_BUCK - 1) / NODES_PER_BUCK)   // 391
#define CAP 9216                 // padded bucket capacity (mean 8192, +11 sigma)

typedef unsigned long long ull;

// ---- bf16 helpers (RNE) ----
__device__ inline unsigned bf16pair(float a, float b) {
    unsigned ua = __float_as_uint(a), ub = __float_as_uint(b);
    unsigned r0 = (ua + 0x7fffu + ((ua >> 16) & 1u)) >> 16;
    unsigned r1 = (ub + 0x7fffu + ((ub >> 16) & 1u)) >> 16;
    return r0 | (r1 << 16);
}
__device__ inline float blo(unsigned u) { return __uint_as_float(u << 16); }
__device__ inline float bhi(unsigned u) { return __uint_as_float(u & 0xffff0000u); }

// accumulate 8 bf16 dims (one uint4) * w into s[0..7]
__device__ inline void acc8(float* s, uint4 g, float w) {
    s[0] = fmaf(w, blo(g.x), s[0]); s[1] = fmaf(w, bhi(g.x), s[1]);
    s[2] = fmaf(w, blo(g.y), s[2]); s[3] = fmaf(w, bhi(g.y), s[3]);
    s[4] = fmaf(w, blo(g.z), s[4]); s[5] = fmaf(w, bhi(g.z), s[5]);
    s[6] = fmaf(w, blo(g.w), s[6]); s[7] = fmaf(w, bhi(g.w), s[7]);
}

// init: E0(bf16) = concat(ue, ie). Block 0 inits bucket cursors.
// Fused flag pass: flags[n]=1 for batch nodes (no zeroing: poison 0xAA != 1;
// spurious stale 1 only costs harmless extra compute in the gated pull).
__global__ void init_emb_kernel(const float* __restrict__ ue,
                                const float* __restrict__ ie,
                                unsigned* __restrict__ E0,
                                int* __restrict__ bucketCursor,
                                unsigned char* __restrict__ flags,
                                const int* __restrict__ users,
                                const int* __restrict__ items) {
    int idx = blockIdx.x * blockDim.x + threadIdx.x;   // per float4 (4 dims)
    if (blockIdx.x == 0 && threadIdx.x < 256) {
        bucketCursor[threadIdx.x]       = threadIdx.x * CAP;
        bucketCursor[threadIdx.x + 256] = (threadIdx.x + 256) * CAP;
    }
    if (idx < BATCH) {
        flags[users[idx]] = 1;
    } else if (idx < 2 * BATCH) {
        flags[NUM_USERS + items[idx - BATCH]] = 1;
    }
    const int total = N_NODES * (EMB_DIM / 4);
    if (idx >= total) return;
    const int uoff = NUM_USERS * (EMB_DIM / 4);
    float4 v;
    if (idx < uoff) v = ((const float4*)ue)[idx];
    else            v = ((const float4*)ie)[idx - uoff];
    uint2 h;
    h.x = bf16pair(v.x, v.y);
    h.y = bf16pair(v.z, v.w);
    ((uint2*)E0)[idx] = h;
}

// partition edges into padded dst-bucket regions. 1024 threads, 8 edges/thread.
// rec: src(17) | dstLocal(8)<<17 | fix15(val)<<25
// (round-16 form: single shared hist — per-wave split measured SLOWER, r17)
__global__ void partA_kernel(const float* __restrict__ ev,
                             const int*  __restrict__ es,
                             const int*  __restrict__ ed,
                             int* __restrict__ bucketCursor,
                             ull* __restrict__ tmp) {
    __shared__ int hist[NBUCK];
    __shared__ int base[NBUCK];
    __shared__ int cnt2[NBUCK];
    int tid = threadIdx.x;            // 1024
    int e0 = blockIdx.x * TILE_EDGES;

    int      mySrc[8], myDst[8];
    unsigned myQ[8];

    for (int i = tid; i < NBUCK; i += 1024) hist[i] = 0;
    __syncthreads();

    #pragma unroll
    for (int k = 0; k < 8; ++k) {
        int e = e0 + k * 1024 + tid;
        if (e < NNZ) {
            mySrc[k] = es[e];
            myDst[k] = ed[e];
            myQ[k]   = (unsigned)fminf(ev[e] * 32768.f + 0.5f, 32767.f);
            atomicAdd(&hist[((unsigned)myDst[k]) >> ABITS], 1);
        } else {
            myDst[k] = -1;
        }
    }
    __syncthreads();

    for (int i = tid; i < NBUCK; i += 1024) {
        int c = hist[i];
        base[i] = c ? atomicAdd(&bucketCursor[i], c) : 0;
        cnt2[i] = 0;
    }
    __syncthreads();

    #pragma unroll
    for (int k = 0; k < 8; ++k) {
        int dst = myDst[k];
        if (dst < 0) continue;
        int b = ((unsigned)dst) >> ABITS;
        int pos = base[b] + atomicAdd(&cnt2[b], 1);
        if (pos < (b + 1) * CAP) {   // statistically unreachable overflow guard
            ull rec = (ull)(unsigned)(mySrc[k] | ((dst & (NODES_PER_BUCK - 1)) << 17))
                    | ((ull)myQ[k] << 25);
            tmp[pos] = rec;
        }
    }
}

// partB: per bucket — single-pass: register-cache records (<=9/thread), node degrees
// + rowStart via LDS scan, scatter from registers to padded-CSR positions.
// sorted rec (u32): src(17) | fix15(val)<<17
__global__ void partB_kernel(const ull* __restrict__ tmp,
                             const int* __restrict__ bucketCursor,
                             int* __restrict__ rowStart,
                             int* __restrict__ deg,
                             unsigned* __restrict__ sorted) {
    __shared__ int cnt[NODES_PER_BUCK];
    __shared__ int sc[NODES_PER_BUCK];
    __shared__ int cur[NODES_PER_BUCK];
    int b = blockIdx.x;
    int tid = threadIdx.x;           // 1024
    int nodeLo = b << ABITS;
    int startE = b * CAP;
    int endE   = bucketCursor[b];    // base + edges in bucket

    if (tid < NODES_PER_BUCK) cnt[tid] = 0;
    __syncthreads();

    ull myRec[9];
    int nRec = 0;
    #pragma unroll
    for (int k = 0; k < 9; ++k) {
        int i = startE + k * 1024 + tid;
        if (i < endE) {
            myRec[k] = tmp[i];
            nRec = k + 1;
            atomicAdd(&cnt[(int)((myRec[k] >> 17) & (NODES_PER_BUCK - 1))], 1);
        }
    }
    __syncthreads();

    if (tid < NODES_PER_BUCK) sc[tid] = cnt[tid];
    __syncthreads();
    for (int o = 1; o < NODES_PER_BUCK; o <<= 1) {
        int add = 0;
        if (tid < NODES_PER_BUCK && tid >= o) add = sc[tid - o];
        __syncthreads();
        if (tid < NODES_PER_BUCK) sc[tid] += add;
        __syncthreads();
    }
    if (tid < NODES_PER_BUCK) {
        int node = nodeLo + tid;
        int rs = startE + sc[tid] - cnt[tid];
        cur[tid] = rs;
        if (node < N_NODES) {
            rowStart[node] = rs;          // index into padded sorted array
            deg[node] = cnt[tid];
        }
    }
    __syncthreads();

    for (int k = 0; k < nRec; ++k) {
        ull rec = myRec[k];
        int dl = (int)((rec >> 17) & (NODES_PER_BUCK - 1));
        unsigned o = (unsigned)(rec & 0x1FFFFULL) | ((unsigned)((rec >> 25) & 0x7FFF) << 17);
        int pos = atomicAdd(&cur[dl], 1);
        sorted[pos] = o;
    }
}

// ---- pull: one wave per dst node; lane = (eg=lane>>3, d8=lane&7).
// u32 edge records; uint4 bf16 gathers; 32 edges in flight. Byte-flag gate on last layer.
__global__ void pull_kernel(const uint4* __restrict__ A16,
                            uint4* __restrict__ B16,
                            const unsigned* __restrict__ sorted,
                            const int* __restrict__ rowStart,
                            const int* __restrict__ deg,
                            const unsigned char* __restrict__ flags,
                            int gate) {
    int t = blockIdx.x * blockDim.x + threadIdx.x;
    int node = t >> 6;
    if (node >= N_NODES) return;
    if (gate && flags[node] != 1) return;   // wave-uniform
    int lane = t & 63;
    int eg = lane >> 3;      // 0..7
    int d8 = lane & 7;       // dim octet (16 B)
    int start = rowStart[node];
    int cnt   = deg[node];   // wave-uniform
    const unsigned* ep = sorted + start;
    const float k15 = 1.f / 32768.f;

    float s[8] = {0.f,0.f,0.f,0.f,0.f,0.f,0.f,0.f};
    int j = 0;
    while (j + 32 <= cnt) {
        unsigned r0 = ep[j + eg], r1 = ep[j + 8 + eg];
        unsigned r2 = ep[j + 16 + eg], r3 = ep[j + 24 + eg];
        uint4 g0 = A16[(((long long)(r0 & 0x1FFFFu)) << 3) + d8];
        uint4 g1 = A16[(((long long)(r1 & 0x1FFFFu)) << 3) + d8];
        uint4 g2 = A16[(((long long)(r2 & 0x1FFFFu)) << 3) + d8];
        uint4 g3 = A16[(((long long)(r3 & 0x1FFFFu)) << 3) + d8];
        acc8(s, g0, (float)(r0 >> 17) * k15);
        acc8(s, g1, (float)(r1 >> 17) * k15);
        acc8(s, g2, (float)(r2 >> 17) * k15);
        acc8(s, g3, (float)(r3 >> 17) * k15);
        j += 32;
    }
    while (j + 16 <= cnt) {
        unsigned r0 = ep[j + eg], r1 = ep[j + 8 + eg];
        uint4 g0 = A16[(((long long)(r0 & 0x1FFFFu)) << 3) + d8];
        uint4 g1 = A16[(((long long)(r1 & 0x1FFFFu)) << 3) + d8];
        acc8(s, g0, (float)(r0 >> 17) * k15);
        acc8(s, g1, (float)(r1 >> 17) * k15);
        j += 16;
    }
    for (; j < cnt; j += 8) {
        int idx = j + eg;
        unsigned r = (idx < cnt) ? ep[idx] : 0u;   // r=0 -> w=0
        uint4 g = A16[(((long long)(r & 0x1FFFFu)) << 3) + d8];
        acc8(s, g, (float)(r >> 17) * k15);
    }
    #pragma unroll
    for (int k = 0; k < 8; ++k) {
        s[k] += __shfl_xor(s[k], 8, 64);
        s[k] += __shfl_xor(s[k], 16, 64);
        s[k] += __shfl_xor(s[k], 32, 64);
    }
    if (eg == 0) {
        uint4 h;
        h.x = bf16pair(s[0], s[1]);
        h.y = bf16pair(s[2], s[3]);
        h.z = bf16pair(s[4], s[5]);
        h.w = bf16pair(s[6], s[7]);
        B16[(((long long)node) << 3) + d8] = h;
    }
}

// dot: half-wave (32 lanes) per batch element; lane covers 2 dims (one uint).
// gamma = dot( sum_l U_l , sum_l I_l ) / 16, layers read from E0,B1,B2,B3.
__global__ void dot_kernel(const unsigned* __restrict__ E0,
                           const unsigned* __restrict__ B1,
                           const unsigned* __restrict__ B2,
                           const unsigned* __restrict__ B3,
                           const int* __restrict__ users,
                           const int* __restrict__ items,
                           float* __restrict__ out) {
    int t = blockIdx.x * blockDim.x + threadIdx.x;
    int b = t >> 5;
    int lane = t & 31;
    if (b >= BATCH) return;
    long long uo = ((long long)users[b] << 5) + lane;
    long long io = ((long long)(items[b] + NUM_USERS) << 5) + lane;
    unsigned a0 = E0[uo], a1 = B1[uo], a2 = B2[uo], a3 = B3[uo];
    unsigned c0 = E0[io], c1 = B1[io], c2 = B2[io], c3 = B3[io];
    float ux = (blo(a0) + blo(a1)) + (blo(a2) + blo(a3));
    float uy = (bhi(a0) + bhi(a1)) + (bhi(a2) + bhi(a3));
    float ix = (blo(c0) + blo(c1)) + (blo(c2) + blo(c3));
    float iy = (bhi(c0) + bhi(c1)) + (bhi(c2) + bhi(c3));
    float p = ux * ix + uy * iy;
    #pragma unroll
    for (int off = 16; off >= 1; off >>= 1)
        p += __shfl_xor(p, off, 64);   // stays within the aligned 32-group
    if (lane == 0) out[b] = p * 0.0625f;
}

extern "C" void kernel_launch(void* const* d_in, const int* in_sizes, int n_in,
                              void* d_out, int out_size, void* d_ws, size_t ws_size,
                              hipStream_t stream) {
    const float* user_emb = (const float*)d_in[0];
    const float* item_emb = (const float*)d_in[1];
    const float* edge_val = (const float*)d_in[2];
    const int*   edge_src = (const int*)d_in[3];
    const int*   edge_dst = (const int*)d_in[4];
    const int*   users    = (const int*)d_in[5];
    const int*   items    = (const int*)d_in[6];
    float* out = (float*)d_out;

    const size_t emb16Bytes = (size_t)N_NODES * EMB_DIM * 2;               // 12.8 MB
    const size_t sortBytes  = (size_t)NBUCK_USED * CAP * sizeof(unsigned); // 14.4 MB
    const size_t tmpBytes   = (size_t)NBUCK_USED * CAP * sizeof(ull);      // 28.8 MB
    const size_t nodeBytes  = (size_t)N_NODES * sizeof(int);               // 400 KB

    char* w = (char*)d_ws;
    unsigned* E0           = (unsigned*)(w); w += emb16Bytes;
    unsigned* B1           = (unsigned*)(w); w += emb16Bytes;
    unsigned* B2           = (unsigned*)(w); w += emb16Bytes;
    unsigned* B3           = (unsigned*)(w); w += emb16Bytes;
    unsigned* sorted       = (unsigned*)(w); w += sortBytes;
    ull*      tmp          = (ull*)(w);      w += tmpBytes;
    int*      deg          = (int*)(w);      w += nodeBytes;
    int*      rowStart     = (int*)(w);      w += nodeBytes;
    int*      bucketCursor = (int*)(w);      w += NBUCK * sizeof(int);
    unsigned char* flags   = (unsigned char*)(w); w += N_NODES;

    const int vecTotal   = N_NODES * (EMB_DIM / 4);
    const int initBlocks = (vecTotal + 255) / 256;
    const int tileBlocks = (NNZ + TILE_EDGES - 1) / TILE_EDGES;   // 391

    init_emb_kernel<<<initBlocks, 256, 0, stream>>>(user_emb, item_emb, E0,
                                                    bucketCursor, flags, users, items);

    partA_kernel<<<tileBlocks, 1024, 0, stream>>>(edge_val, edge_src, edge_dst,
                                                  bucketCursor, tmp);
    partB_kernel<<<NBUCK_USED, 1024, 0, stream>>>(tmp, bucketCursor,
                                                  rowStart, deg, sorted);

    const int pullBlocks = (N_NODES * 64 + 255) / 256;
    pull_kernel<<<pullBlocks, 256, 0, stream>>>((const uint4*)E0, (uint4*)B1,
                                                sorted, rowStart, deg, flags, 0);
    pull_kernel<<<pullBlocks, 256, 0, stream>>>((const uint4*)B1, (uint4*)B2,
                                                sorted, rowStart, deg, flags, 0);
    pull_kernel<<<pullBlocks, 256, 0, stream>>>((const uint4*)B2, (uint4*)B3,
                                                sorted, rowStart, deg, flags, 1);

    const int dotBlocks = (BATCH * 32 + 255) / 256;
    dot_kernel<<<dotBlocks, 256, 0, stream>>>(E0, B1, B2, B3, users, items, out);
}